// Round 13
// baseline (262.607 us; speedup 1.0000x reference)
//
#include <hip/hip_runtime.h>
#include <hip/hip_bf16.h>
#include <cstdint>
#include <cstddef>

#define N_ATOMS 10000
#define NSTRUCT 100
#define NP 4
#define NS 4
#define NFEAT 4096
#define HID 256
#define APAD 10240   // 80 tiles of 128

// prep-kernel block ranges
#define PB_FEAT  10000                    // [0, 10000): power spectrum
#define PB_W0    (PB_FEAT + 4096)         // w0cvt: 8 x 128 x 4 tiles
#define PB_W1    (PB_W0 + 256)            // w1cvt: 8 x 8 x 4 tiles
#define PB_ZERO  (PB_W1 + 480)            // fh tail rows 10000..10239
#define PB_TOTAL (PB_ZERO + 1)            // + out zero

typedef __attribute__((ext_vector_type(8))) _Float16 f16x8;
typedef __attribute__((ext_vector_type(8))) ushort u16x8;
typedef __attribute__((ext_vector_type(4))) float f32x4;

__device__ __forceinline__ float silu(float x) {
  return x / (1.f + __expf(-x));
}
__device__ __forceinline__ ushort f2h(float x) {
  _Float16 h = (_Float16)x;
  return *reinterpret_cast<ushort*>(&h);
}

typedef __attribute__((address_space(3))) uint32_t lds_u32;
typedef const __attribute__((address_space(1))) uint32_t glb_u32;
__device__ __forceinline__ void glds16(const ushort* g, ushort* l) {
  __builtin_amdgcn_global_load_lds((glb_u32*)g, (lds_u32*)l, 16, 0, 0);
}

// ---------------- Kernel P: fused prep -------------------------------------
// blocks [0,10000): feat | [..): w0cvt | w1cvt | fh-tail zero | out zero
__global__ __launch_bounds__(256) void prep_kernel(
    const float* __restrict__ c0, const float* __restrict__ c1,
    const float* __restrict__ c2, const float* __restrict__ c3,
    const float* __restrict__ W0, const float* __restrict__ W1,
    ushort* __restrict__ fh, ushort* __restrict__ W0t,
    ushort* __restrict__ W1t, float* __restrict__ out) {
  __shared__ float shbuf[32 * 33];   // feat uses first 512; cvt uses 32x33
  int b = blockIdx.x;
  int tid = threadIdx.x;

  if (b < PB_FEAT) {
    // ---- power spectrum -> fp16 ----
    int a = b;
    float* cs = shbuf;
    for (int e = tid; e < 512; e += 256) {
      float v;
      if (e < 32)       v = c0[a * 32  + e];
      else if (e < 128) v = c1[a * 96  + (e - 32)];
      else if (e < 288) v = c2[a * 160 + (e - 128)];
      else              v = c3[a * 224 + (e - 288)];
      cs[e] = v;
    }
    __syncthreads();
    const float cg[4]  = {1.0f, 0.5773502691896258f, 0.4472135954999579f, 0.3779644730092272f};
    const int  off[4]  = {0, 32, 128, 288};
    const int  nm[4]   = {1, 3, 5, 7};
#pragma unroll
    for (int it = 0; it < 2; ++it) {
      int cc = tid + it * 256;
      int l = cc >> 7;
      int rem = cc & 127;
      int q = rem >> 2, rc = (rem & 3) * 8;
      const float* base = cs + off[l];
      float s[8] = {0.f, 0.f, 0.f, 0.f, 0.f, 0.f, 0.f, 0.f};
      for (int m = 0; m < nm[l]; ++m) {
        float bq = base[m * 32 + q];
        float4 v0 = *reinterpret_cast<const float4*>(&base[m * 32 + rc]);
        float4 v1 = *reinterpret_cast<const float4*>(&base[m * 32 + rc + 4]);
        s[0] += bq * v0.x; s[1] += bq * v0.y; s[2] += bq * v0.z; s[3] += bq * v0.w;
        s[4] += bq * v1.x; s[5] += bq * v1.y; s[6] += bq * v1.z; s[7] += bq * v1.w;
      }
      u16x8 o;
#pragma unroll
      for (int t = 0; t < 8; ++t) o[t] = f2h(s[t] * cg[l]);
      *reinterpret_cast<u16x8*>(&fh[(size_t)a * NFEAT + cc * 8]) = o;
    }
  } else if (b < PB_W0) {
    // ---- W0 [p][k][n] -> W0t [p][n][k] fp16, 32x32 tiles ----
    int idx = b - PB_FEAT;          // 4096 = 8(n) x 128(k) x 4(p)
    int nx = idx & 7, ky = (idx >> 3) & 127, p = idx >> 10;
    int kt = ky * 32, nt = nx * 32;
    int lx = tid & 31, ly = tid >> 5;
    float (*t)[33] = (float(*)[33])shbuf;
    const float* src = W0 + (size_t)p * NFEAT * HID;
#pragma unroll
    for (int i = 0; i < 4; ++i)
      t[ly + i * 8][lx] = src[(size_t)(kt + ly + i * 8) * HID + nt + lx];
    __syncthreads();
    ushort* dst = W0t + (size_t)p * HID * NFEAT;
#pragma unroll
    for (int i = 0; i < 4; ++i)
      dst[(size_t)(nt + ly + i * 8) * NFEAT + kt + lx] = f2h(t[lx][ly + i * 8]);
  } else if (b < PB_W1) {
    // ---- W1 [p][k][n] -> W1t [p][n][k] fp16 ----
    int idx = b - PB_W0;            // 256 = 8 x 8 x 4
    int nx = idx & 7, ky = (idx >> 3) & 7, p = idx >> 6;
    int kt = ky * 32, nt = nx * 32;
    int lx = tid & 31, ly = tid >> 5;
    float (*t)[33] = (float(*)[33])shbuf;
    const float* src = W1 + (size_t)p * HID * HID;
#pragma unroll
    for (int i = 0; i < 4; ++i)
      t[ly + i * 8][lx] = src[(size_t)(kt + ly + i * 8) * HID + nt + lx];
    __syncthreads();
    ushort* dst = W1t + (size_t)p * HID * HID;
#pragma unroll
    for (int i = 0; i < 4; ++i)
      dst[(size_t)(nt + ly + i * 8) * HID + kt + lx] = f2h(t[lx][ly + i * 8]);
  } else if (b < PB_ZERO) {
    // ---- zero fh rows [10000, 10240) : 480 blocks x 2048 ushorts ----
    int idx = b - PB_W1;
    size_t base = (size_t)N_ATOMS * NFEAT + (size_t)idx * 2048 + tid * 8;
    u16x8 z = (u16x8){0, 0, 0, 0, 0, 0, 0, 0};
    *reinterpret_cast<u16x8*>(&fh[base]) = z;
  } else {
    // ---- zero out[100] ----
    if (tid < NSTRUCT) out[tid] = 0.f;
  }
}

// ---------------- Kernel B: fp16 MFMA GEMM0, 128x128, BK=32 (R8 shape) -----
// LDS: 64 phys rows x 128B; phys (pr,pc) holds logical (m_half=lg>>2, kc=lg&3)
// of m-row pr + 64*m_half, lg = pc^(pr&7). Conflict-free b128 reads.
// XCD remap: linear&7 = m-group so the 8 n-tiles of an m-tile share one XCD L2.
__global__ __launch_bounds__(256) void gemm0_mfma(
    const ushort* __restrict__ fh, const ushort* __restrict__ W0t,
    const float* __restrict__ combW, const int* __restrict__ species,
    ushort* __restrict__ h0f) {
  __shared__ ushort As[64 * 64];   // 8KB
  __shared__ ushort Bs[64 * 64];   // 8KB
  int tid = threadIdx.x;
  int linear = blockIdx.y * 8 + blockIdx.x;
  int xc = linear & 7, sq = linear >> 3;
  int bm = ((sq >> 3) * 8 + xc) * 128;   // m-tile
  int bn = (sq & 7) * 128;               // n-tile
  int wid = tid >> 6, lane = tid & 63;
  int wm = (wid >> 1) * 64, wn = (wid & 1) * 64;
  int mh = wid >> 1, nh = wid & 1;

  int pr = tid >> 3, pc = tid & 7;
  int lg = pc ^ (pr & 7);
  int mhalf = lg >> 2, kc = lg & 3;
  const ushort* gaA1 = fh  + ((size_t)(bm + pr + 64 * mhalf) * NFEAT + kc * 8);
  const ushort* gaA2 = gaA1 + (size_t)32 * NFEAT;
  const ushort* gaB1 = W0t + ((size_t)(bn + pr + 64 * mhalf) * NFEAT + kc * 8);
  const ushort* gaB2 = gaB1 + (size_t)32 * NFEAT;
  ushort* lA = As + tid * 8;
  ushort* lB = Bs + tid * 8;

  f32x4 acc[4][4];
#pragma unroll
  for (int i = 0; i < 4; ++i)
#pragma unroll
    for (int j = 0; j < 4; ++j) acc[i][j] = (f32x4){0.f, 0.f, 0.f, 0.f};

  int mrow = lane & 15;
  int h7 = mrow & 7;
  int qv = lane >> 4;
  int pcA = ((mh << 2) | qv) ^ h7;
  int pcB = ((nh << 2) | qv) ^ h7;

  for (int k0 = 0; k0 < NFEAT; k0 += 32) {
    glds16(gaA1 + k0, lA);
    glds16(gaA2 + k0, lA + 2048);
    glds16(gaB1 + k0, lB);
    glds16(gaB2 + k0, lB + 2048);
    __syncthreads();

    f16x8 af[4], bf[4];
#pragma unroll
    for (int i = 0; i < 4; ++i) {
      af[i] = *reinterpret_cast<const f16x8*>(&As[(i * 16 + mrow) * 64 + pcA * 8]);
      bf[i] = *reinterpret_cast<const f16x8*>(&Bs[(i * 16 + mrow) * 64 + pcB * 8]);
    }
#pragma unroll
    for (int i = 0; i < 4; ++i)
#pragma unroll
      for (int j = 0; j < 4; ++j)
        acc[i][j] = __builtin_amdgcn_mfma_f32_16x16x32_f16(af[i], bf[j], acc[i][j], 0, 0, 0);
    __syncthreads();
  }

  int p = bn >> 8;
  int col = lane & 15, rbase = (lane >> 4) * 4;
#pragma unroll
  for (int i = 0; i < 4; ++i) {
#pragma unroll
    for (int r = 0; r < 4; ++r) {
      int m = bm + wm + i * 16 + rbase + r;
      bool live = (m < N_ATOMS);
      float pw = live ? combW[p * NS + species[m]] : 0.f;
#pragma unroll
      for (int j = 0; j < 4; ++j) {
        int n = bn + wn + j * 16 + col;
        float v = live ? silu(pw * acc[i][j][r]) : 0.f;
        h0f[(size_t)m * 1024 + n] = f2h(v);
      }
    }
  }
}

// ---------------- Kernel C: layer-1 all-register MFMA + W2 dot + seg-sum ---
// 128x64 tile, K=256, no LDS staging, no K-loop barriers. A and B fragments
// loaded straight to registers (h0f rows: wave covers 16 x 64B cachelines per
// load instr). Grid remapped so m-tile == linear (mod 8) -> same XCD that
// produced the h0f tile in gemm0.
__global__ __launch_bounds__(256) void mlp1_mfma(
    const ushort* __restrict__ h0f, const ushort* __restrict__ W1t,
    const float* __restrict__ W2, const int* __restrict__ sid,
    float* __restrict__ out) {
  __shared__ float sout[NSTRUCT];
  int tid = threadIdx.x;
  int linear = blockIdx.y * 16 + blockIdx.x;   // 0..1279
  int xc = linear & 7, s = linear >> 3;        // s in [0,160)
  int bm = ((s >> 4) * 8 + xc) * 128;          // m-tile: mt&7 == xc
  int bn = (s & 15) * 64;                      // n in [0,1024)
  int p  = bn >> 8;
  int wid = tid >> 6, lane = tid & 63;
  int wm = (wid >> 1) * 64;
  int wn = (wid & 1) * 32;

  if (tid < NSTRUCT) sout[tid] = 0.f;

  int mrow = lane & 15;
  int qv = lane >> 4;

  // B fragments: n = (bn&255)+wn+j*16+mrow, k = ki*32 + qv*8 .. +8
  const ushort* wb = W1t + (size_t)p * HID * HID;
  f16x8 breg[2][8];
#pragma unroll
  for (int j = 0; j < 2; ++j) {
    const ushort* row = wb + (size_t)((bn & 255) + wn + j * 16 + mrow) * 256 + qv * 8;
#pragma unroll
    for (int ki = 0; ki < 8; ++ki)
      breg[j][ki] = *reinterpret_cast<const f16x8*>(row + ki * 32);
  }

  f32x4 acc[4][2];
#pragma unroll
  for (int i = 0; i < 4; ++i)
#pragma unroll
    for (int j = 0; j < 2; ++j) acc[i][j] = (f32x4){0.f, 0.f, 0.f, 0.f};

  // A rows for this lane's 4 m-subtiles
  const ushort* arow[4];
#pragma unroll
  for (int i = 0; i < 4; ++i)
    arow[i] = h0f + (size_t)(bm + wm + i * 16 + mrow) * 1024 + p * 256 + qv * 8;

#pragma unroll
  for (int ki = 0; ki < 8; ++ki) {
    f16x8 af[4];
#pragma unroll
    for (int i = 0; i < 4; ++i)
      af[i] = *reinterpret_cast<const f16x8*>(arow[i] + ki * 32);
#pragma unroll
    for (int i = 0; i < 4; ++i)
#pragma unroll
      for (int j = 0; j < 2; ++j)
        acc[i][j] = __builtin_amdgcn_mfma_f32_16x16x32_f16(af[i], breg[j][ki], acc[i][j], 0, 0, 0);
  }

  // fused layer-2 + segment-sum epilogue (LDS-staged)
  __syncthreads();                 // sout zero-init visible to all
  int col = lane & 15, quad = lane >> 4;
  float w2j0 = W2[bn + wn + col];
  float w2j1 = W2[bn + wn + 16 + col];
#pragma unroll
  for (int i = 0; i < 4; ++i) {
#pragma unroll
    for (int r = 0; r < 4; ++r) {
      float v = silu(acc[i][0][r]) * w2j0 + silu(acc[i][1][r]) * w2j1;
      v += __shfl_xor(v, 1, 64);
      v += __shfl_xor(v, 2, 64);
      v += __shfl_xor(v, 4, 64);
      v += __shfl_xor(v, 8, 64);
      if (col == 0) {
        int m = bm + wm + i * 16 + quad * 4 + r;
        if (m < N_ATOMS) atomicAdd(&sout[sid[m]], v);   // LDS atomic
      }
    }
  }
  __syncthreads();
  if (tid < NSTRUCT) {
    float v = sout[tid];
    if (v != 0.f) atomicAdd(&out[tid], v);              // ~2-3 per block
  }
}

extern "C" void kernel_launch(void* const* d_in, const int* in_sizes, int n_in,
                              void* d_out, int out_size, void* d_ws, size_t ws_size,
                              hipStream_t stream) {
  const float* c0      = (const float*)d_in[0];
  const float* c1      = (const float*)d_in[1];
  const float* c2      = (const float*)d_in[2];
  const float* c3      = (const float*)d_in[3];
  const int*   species = (const int*)d_in[4];
  const int*   sid     = (const int*)d_in[5];
  const float* combW   = (const float*)d_in[6];
  const float* W0      = (const float*)d_in[7];
  const float* W1      = (const float*)d_in[8];
  const float* W2      = (const float*)d_in[9];
  float*       out     = (float*)d_out;

  // ws: fh 83.9MB | W0t 8.4MB | W1t 0.5MB | h0f 21MB = ~114MB
  ushort* fh  = (ushort*)d_ws;
  ushort* W0t = fh  + (size_t)APAD * NFEAT;
  ushort* W1t = W0t + (size_t)NP * HID * NFEAT;
  ushort* h0f = W1t + (size_t)NP * HID * HID;

  prep_kernel<<<PB_TOTAL, 256, 0, stream>>>(c0, c1, c2, c3, W0, W1,
                                            fh, W0t, W1t, out);

  dim3 g2(8, APAD / 128);    // 8 n-tiles x 80 remapped slots (R8 shape)
  gemm0_mfma<<<g2, 256, 0, stream>>>(fh, W0t, combW, species, h0f);

  dim3 g3(16, APAD / 128);   // 1280 blocks, XCD-remapped inside
  mlp1_mfma<<<g3, 256, 0, stream>>>(h0f, W1t, W2, sid, out);
}

// Round 14
// 256.199 us; speedup vs baseline: 1.0250x; 1.0250x over previous
//
#include <hip/hip_runtime.h>
#include <hip/hip_bf16.h>
#include <cstdint>
#include <cstddef>

#define N_ATOMS 10000
#define NSTRUCT 100
#define NP 4
#define NS 4
#define NFEAT 4096
#define HID 256
#define APAD 10240   // 80 tiles of 128

// prep-kernel block ranges
#define PB_FEAT  10000                    // [0, 10000): power spectrum
#define PB_W0    (PB_FEAT + 4096)         // w0cvt: 8 x 128 x 4 tiles
#define PB_W1    (PB_W0 + 256)            // w1cvt: 8 x 8 x 4 tiles
#define PB_ZERO  (PB_W1 + 480)            // fh tail rows 10000..10239
#define PB_TOTAL (PB_ZERO + 1)            // + out zero

typedef __attribute__((ext_vector_type(8))) _Float16 f16x8;
typedef __attribute__((ext_vector_type(8))) ushort u16x8;
typedef __attribute__((ext_vector_type(4))) float f32x4;

__device__ __forceinline__ float silu(float x) {
  return x / (1.f + __expf(-x));
}
__device__ __forceinline__ ushort f2h(float x) {
  _Float16 h = (_Float16)x;
  return *reinterpret_cast<ushort*>(&h);
}

typedef __attribute__((address_space(3))) uint32_t lds_u32;
typedef const __attribute__((address_space(1))) uint32_t glb_u32;
__device__ __forceinline__ void glds16(const ushort* g, ushort* l) {
  __builtin_amdgcn_global_load_lds((glb_u32*)g, (lds_u32*)l, 16, 0, 0);
}

// ---------------- Kernel P: fused prep -------------------------------------
__global__ __launch_bounds__(256) void prep_kernel(
    const float* __restrict__ c0, const float* __restrict__ c1,
    const float* __restrict__ c2, const float* __restrict__ c3,
    const float* __restrict__ W0, const float* __restrict__ W1,
    ushort* __restrict__ fh, ushort* __restrict__ W0t,
    ushort* __restrict__ W1t, float* __restrict__ out) {
  __shared__ float shbuf[32 * 33];
  int b = blockIdx.x;
  int tid = threadIdx.x;

  if (b < PB_FEAT) {
    int a = b;
    float* cs = shbuf;
    for (int e = tid; e < 512; e += 256) {
      float v;
      if (e < 32)       v = c0[a * 32  + e];
      else if (e < 128) v = c1[a * 96  + (e - 32)];
      else if (e < 288) v = c2[a * 160 + (e - 128)];
      else              v = c3[a * 224 + (e - 288)];
      cs[e] = v;
    }
    __syncthreads();
    const float cg[4]  = {1.0f, 0.5773502691896258f, 0.4472135954999579f, 0.3779644730092272f};
    const int  off[4]  = {0, 32, 128, 288};
    const int  nm[4]   = {1, 3, 5, 7};
#pragma unroll
    for (int it = 0; it < 2; ++it) {
      int cc = tid + it * 256;
      int l = cc >> 7;
      int rem = cc & 127;
      int q = rem >> 2, rc = (rem & 3) * 8;
      const float* base = cs + off[l];
      float s[8] = {0.f, 0.f, 0.f, 0.f, 0.f, 0.f, 0.f, 0.f};
      for (int m = 0; m < nm[l]; ++m) {
        float bq = base[m * 32 + q];
        float4 v0 = *reinterpret_cast<const float4*>(&base[m * 32 + rc]);
        float4 v1 = *reinterpret_cast<const float4*>(&base[m * 32 + rc + 4]);
        s[0] += bq * v0.x; s[1] += bq * v0.y; s[2] += bq * v0.z; s[3] += bq * v0.w;
        s[4] += bq * v1.x; s[5] += bq * v1.y; s[6] += bq * v1.z; s[7] += bq * v1.w;
      }
      u16x8 o;
#pragma unroll
      for (int t = 0; t < 8; ++t) o[t] = f2h(s[t] * cg[l]);
      *reinterpret_cast<u16x8*>(&fh[(size_t)a * NFEAT + cc * 8]) = o;
    }
  } else if (b < PB_W0) {
    int idx = b - PB_FEAT;
    int nx = idx & 7, ky = (idx >> 3) & 127, p = idx >> 10;
    int kt = ky * 32, nt = nx * 32;
    int lx = tid & 31, ly = tid >> 5;
    float (*t)[33] = (float(*)[33])shbuf;
    const float* src = W0 + (size_t)p * NFEAT * HID;
#pragma unroll
    for (int i = 0; i < 4; ++i)
      t[ly + i * 8][lx] = src[(size_t)(kt + ly + i * 8) * HID + nt + lx];
    __syncthreads();
    ushort* dst = W0t + (size_t)p * HID * NFEAT;
#pragma unroll
    for (int i = 0; i < 4; ++i)
      dst[(size_t)(nt + ly + i * 8) * NFEAT + kt + lx] = f2h(t[lx][ly + i * 8]);
  } else if (b < PB_W1) {
    int idx = b - PB_W0;
    int nx = idx & 7, ky = (idx >> 3) & 7, p = idx >> 6;
    int kt = ky * 32, nt = nx * 32;
    int lx = tid & 31, ly = tid >> 5;
    float (*t)[33] = (float(*)[33])shbuf;
    const float* src = W1 + (size_t)p * HID * HID;
#pragma unroll
    for (int i = 0; i < 4; ++i)
      t[ly + i * 8][lx] = src[(size_t)(kt + ly + i * 8) * HID + nt + lx];
    __syncthreads();
    ushort* dst = W1t + (size_t)p * HID * HID;
#pragma unroll
    for (int i = 0; i < 4; ++i)
      dst[(size_t)(nt + ly + i * 8) * HID + kt + lx] = f2h(t[lx][ly + i * 8]);
  } else if (b < PB_ZERO) {
    int idx = b - PB_W1;
    size_t base = (size_t)N_ATOMS * NFEAT + (size_t)idx * 2048 + tid * 8;
    u16x8 z = (u16x8){0, 0, 0, 0, 0, 0, 0, 0};
    *reinterpret_cast<u16x8*>(&fh[base]) = z;
  } else {
    if (tid < NSTRUCT) out[tid] = 0.f;
  }
}

// ---------------- Kernel B: fp16 MFMA GEMM0, 128x128, BK=32 (R8 shape) -----
__global__ __launch_bounds__(256) void gemm0_mfma(
    const ushort* __restrict__ fh, const ushort* __restrict__ W0t,
    const float* __restrict__ combW, const int* __restrict__ species,
    ushort* __restrict__ h0f) {
  __shared__ ushort As[64 * 64];   // 8KB
  __shared__ ushort Bs[64 * 64];   // 8KB
  int tid = threadIdx.x;
  int linear = blockIdx.y * 8 + blockIdx.x;
  int xc = linear & 7, sq = linear >> 3;
  int bm = ((sq >> 3) * 8 + xc) * 128;   // m-tile
  int bn = (sq & 7) * 128;               // n-tile
  int wid = tid >> 6, lane = tid & 63;
  int wm = (wid >> 1) * 64, wn = (wid & 1) * 64;
  int mh = wid >> 1, nh = wid & 1;

  int pr = tid >> 3, pc = tid & 7;
  int lg = pc ^ (pr & 7);
  int mhalf = lg >> 2, kc = lg & 3;
  const ushort* gaA1 = fh  + ((size_t)(bm + pr + 64 * mhalf) * NFEAT + kc * 8);
  const ushort* gaA2 = gaA1 + (size_t)32 * NFEAT;
  const ushort* gaB1 = W0t + ((size_t)(bn + pr + 64 * mhalf) * NFEAT + kc * 8);
  const ushort* gaB2 = gaB1 + (size_t)32 * NFEAT;
  ushort* lA = As + tid * 8;
  ushort* lB = Bs + tid * 8;

  f32x4 acc[4][4];
#pragma unroll
  for (int i = 0; i < 4; ++i)
#pragma unroll
    for (int j = 0; j < 4; ++j) acc[i][j] = (f32x4){0.f, 0.f, 0.f, 0.f};

  int mrow = lane & 15;
  int h7 = mrow & 7;
  int qv = lane >> 4;
  int pcA = ((mh << 2) | qv) ^ h7;
  int pcB = ((nh << 2) | qv) ^ h7;

  for (int k0 = 0; k0 < NFEAT; k0 += 32) {
    glds16(gaA1 + k0, lA);
    glds16(gaA2 + k0, lA + 2048);
    glds16(gaB1 + k0, lB);
    glds16(gaB2 + k0, lB + 2048);
    __syncthreads();

    f16x8 af[4], bf[4];
#pragma unroll
    for (int i = 0; i < 4; ++i) {
      af[i] = *reinterpret_cast<const f16x8*>(&As[(i * 16 + mrow) * 64 + pcA * 8]);
      bf[i] = *reinterpret_cast<const f16x8*>(&Bs[(i * 16 + mrow) * 64 + pcB * 8]);
    }
#pragma unroll
    for (int i = 0; i < 4; ++i)
#pragma unroll
      for (int j = 0; j < 4; ++j)
        acc[i][j] = __builtin_amdgcn_mfma_f32_16x16x32_f16(af[i], bf[j], acc[i][j], 0, 0, 0);
    __syncthreads();
  }

  int p = bn >> 8;
  int col = lane & 15, rbase = (lane >> 4) * 4;
#pragma unroll
  for (int i = 0; i < 4; ++i) {
#pragma unroll
    for (int r = 0; r < 4; ++r) {
      int m = bm + wm + i * 16 + rbase + r;
      bool live = (m < N_ATOMS);
      float pw = live ? combW[p * NS + species[m]] : 0.f;
#pragma unroll
      for (int j = 0; j < 4; ++j) {
        int n = bn + wn + j * 16 + col;
        float v = live ? silu(pw * acc[i][j][r]) : 0.f;
        h0f[(size_t)m * 1024 + n] = f2h(v);
      }
    }
  }
}

// ---------------- Kernel C: layer-1 MFMA, whole-A-tile staged once ---------
// Block = 64 m x 64 n; A 64x256 fp16 = 32KB LDS staged via 8 glds16/thread,
// ONE barrier, zero K-loop barriers. B in registers (L2-hot W1t). LDS layout:
// row r (64) x 32 chunks of 16B; chunk pc holds logical k-chunk pc^(r&7)
// (same conflict-free geometry as gemm0). Wave tile 32x32 (2x2 subtiles).
// XCD remap: all blocks of one 128-row h0f group sit on its producing XCD.
__global__ __launch_bounds__(256) void mlp1_mfma(
    const ushort* __restrict__ h0f, const ushort* __restrict__ W1t,
    const float* __restrict__ W2, const int* __restrict__ sid,
    float* __restrict__ out) {
  __shared__ ushort As[64 * 256];   // 32KB
  __shared__ float sout[NSTRUCT];
  int tid = threadIdx.x;
  int linear = blockIdx.x;            // 0..2559
  int xc = linear & 7, s = linear >> 3;      // s in [0,320)
  int nidx = s & 15, t = s >> 4;             // t in [0,20)
  int bm = ((t >> 1) * 8 + xc) * 128 + (t & 1) * 64;   // 64-row tile
  int bn = nidx * 64;
  int p  = bn >> 8;
  int wid = tid >> 6, lane = tid & 63;
  int wm = (wid >> 1) * 32;
  int wn = (wid & 1) * 32;

  if (tid < NSTRUCT) sout[tid] = 0.f;

  int mrow = lane & 15;
  int qv = lane >> 4;

  // stage A: thread covers chunks d = s8*256+tid, r = d>>5, pc = d&31
#pragma unroll
  for (int s8 = 0; s8 < 8; ++s8) {
    int d = s8 * 256 + tid;
    int r = d >> 5, pcs = d & 31;
    int lc = pcs ^ (r & 7);
    glds16(h0f + (size_t)(bm + r) * 1024 + p * 256 + lc * 8, As + d * 8);
  }

  // B fragments while A stages: n = (bn&255)+wn+j*16+mrow, k = ki*32+qv*8
  const ushort* wb = W1t + (size_t)p * HID * HID;
  f16x8 breg[2][8];
#pragma unroll
  for (int j = 0; j < 2; ++j) {
    const ushort* row = wb + (size_t)((bn & 255) + wn + j * 16 + mrow) * 256 + qv * 8;
#pragma unroll
    for (int ki = 0; ki < 8; ++ki)
      breg[j][ki] = *reinterpret_cast<const f16x8*>(row + ki * 32);
  }

  __syncthreads();   // drains glds16 (vmcnt) + sout init visible

  f32x4 acc[2][2];
#pragma unroll
  for (int i = 0; i < 2; ++i)
#pragma unroll
    for (int j = 0; j < 2; ++j) acc[i][j] = (f32x4){0.f, 0.f, 0.f, 0.f};

  int h7 = mrow & 7;
#pragma unroll
  for (int ki = 0; ki < 8; ++ki) {
    f16x8 af[2];
#pragma unroll
    for (int i = 0; i < 2; ++i) {
      int row = wm + i * 16 + mrow;
      int pc2 = (ki * 4 + qv) ^ h7;
      af[i] = *reinterpret_cast<const f16x8*>(&As[row * 256 + pc2 * 8]);
    }
#pragma unroll
    for (int i = 0; i < 2; ++i)
#pragma unroll
      for (int j = 0; j < 2; ++j)
        acc[i][j] = __builtin_amdgcn_mfma_f32_16x16x32_f16(af[i], breg[j][ki], acc[i][j], 0, 0, 0);
  }

  // fused layer-2 + segment-sum epilogue (LDS-staged)
  int col = lane & 15, quad = lane >> 4;
  float w2j0 = W2[bn + wn + col];
  float w2j1 = W2[bn + wn + 16 + col];
#pragma unroll
  for (int i = 0; i < 2; ++i) {
#pragma unroll
    for (int r = 0; r < 4; ++r) {
      float v = silu(acc[i][0][r]) * w2j0 + silu(acc[i][1][r]) * w2j1;
      v += __shfl_xor(v, 1, 64);
      v += __shfl_xor(v, 2, 64);
      v += __shfl_xor(v, 4, 64);
      v += __shfl_xor(v, 8, 64);
      if (col == 0) {
        int m = bm + wm + i * 16 + quad * 4 + r;
        if (m < N_ATOMS) atomicAdd(&sout[sid[m]], v);   // LDS atomic
      }
    }
  }
  __syncthreads();
  if (tid < NSTRUCT) {
    float v = sout[tid];
    if (v != 0.f) atomicAdd(&out[tid], v);              // ~2-3 per block
  }
}

extern "C" void kernel_launch(void* const* d_in, const int* in_sizes, int n_in,
                              void* d_out, int out_size, void* d_ws, size_t ws_size,
                              hipStream_t stream) {
  const float* c0      = (const float*)d_in[0];
  const float* c1      = (const float*)d_in[1];
  const float* c2      = (const float*)d_in[2];
  const float* c3      = (const float*)d_in[3];
  const int*   species = (const int*)d_in[4];
  const int*   sid     = (const int*)d_in[5];
  const float* combW   = (const float*)d_in[6];
  const float* W0      = (const float*)d_in[7];
  const float* W1      = (const float*)d_in[8];
  const float* W2      = (const float*)d_in[9];
  float*       out     = (float*)d_out;

  // ws: fh 83.9MB | W0t 8.4MB | W1t 0.5MB | h0f 21MB = ~114MB
  ushort* fh  = (ushort*)d_ws;
  ushort* W0t = fh  + (size_t)APAD * NFEAT;
  ushort* W1t = W0t + (size_t)NP * HID * NFEAT;
  ushort* h0f = W1t + (size_t)NP * HID * HID;

  prep_kernel<<<PB_TOTAL, 256, 0, stream>>>(c0, c1, c2, c3, W0, W1,
                                            fh, W0t, W1t, out);

  dim3 g2(8, APAD / 128);    // 8 n-tiles x 80 remapped slots (R8 shape)
  gemm0_mfma<<<g2, 256, 0, stream>>>(fh, W0t, combW, species, h0f);

  mlp1_mfma<<<2560, 256, 0, stream>>>(h0f, W1t, W2, sid, out);
}

// Round 15
// 229.001 us; speedup vs baseline: 1.1467x; 1.1188x over previous
//
#include <hip/hip_runtime.h>
#include <hip/hip_bf16.h>
#include <cstdint>
#include <cstddef>

#define N_ATOMS 10000
#define NSTRUCT 100
#define NP 4
#define NS 4
#define NF2 2112      // 4 * 528 symmetric-packed features
#define HID 256
#define APAD 10240    // 80 tiles of 128

// prep-kernel block ranges
#define PB_FEAT  10000                    // [0, 10000): power spectrum
#define PB_W0    (PB_FEAT + 2112)         // w0cvt: 8(n) x 66(k) x 4(p)
#define PB_W1    (PB_W0 + 256)            // w1cvt: 8 x 8 x 4
#define PB_ZERO  (PB_W1 + 248)            // fh tail rows 10000..10239
#define PB_TOTAL (PB_ZERO + 1)            // + out zero

typedef __attribute__((ext_vector_type(8))) _Float16 f16x8;
typedef __attribute__((ext_vector_type(8))) ushort u16x8;
typedef __attribute__((ext_vector_type(4))) float f32x4;

__device__ __forceinline__ float silu(float x) {
  return x / (1.f + __expf(-x));
}
__device__ __forceinline__ ushort f2h(float x) {
  _Float16 h = (_Float16)x;
  return *reinterpret_cast<ushort*>(&h);
}
// triangle decode: idx in [0,528) -> row q (pairs (q,r), q<=r, r-major rows)
__device__ __forceinline__ int tri_q(int idx) {
  int q = (int)((65.0f - sqrtf((float)(4225 - 8 * idx))) * 0.5f);
  if ((q + 1) * (64 - q) / 2 <= idx) ++q;        // offset(q+1) <= idx
  if (q * (65 - q) / 2 > idx) --q;               // offset(q)   >  idx
  return q;
}

typedef __attribute__((address_space(3))) uint32_t lds_u32;
typedef const __attribute__((address_space(1))) uint32_t glb_u32;
__device__ __forceinline__ void glds16(const ushort* g, ushort* l) {
  __builtin_amdgcn_global_load_lds((glb_u32*)g, (lds_u32*)l, 16, 0, 0);
}

// ---------------- Kernel P: fused prep -------------------------------------
__global__ __launch_bounds__(256) void prep_kernel(
    const float* __restrict__ c0, const float* __restrict__ c1,
    const float* __restrict__ c2, const float* __restrict__ c3,
    const float* __restrict__ W0, const float* __restrict__ W1,
    ushort* __restrict__ fh, ushort* __restrict__ W0t,
    ushort* __restrict__ W1t, float* __restrict__ out) {
  __shared__ float shbuf[32 * 33];
  int b = blockIdx.x;
  int tid = threadIdx.x;

  if (b < PB_FEAT) {
    // ---- symmetric-packed power spectrum -> fp16 ----
    int a = b;
    float* cs = shbuf;
    for (int e = tid; e < 512; e += 256) {
      float v;
      if (e < 32)       v = c0[a * 32  + e];
      else if (e < 128) v = c1[a * 96  + (e - 32)];
      else if (e < 288) v = c2[a * 160 + (e - 128)];
      else              v = c3[a * 224 + (e - 288)];
      cs[e] = v;
    }
    __syncthreads();
    const float cg[4]  = {1.0f, 0.5773502691896258f, 0.4472135954999579f, 0.3779644730092272f};
    const int  off[4]  = {0, 32, 128, 288};
    const int  nm[4]   = {1, 3, 5, 7};
#pragma unroll
    for (int it = 0; it < 2; ++it) {
      int cc = tid + it * 256;          // chunk in [0,264): 66 chunks per l
      if (cc >= 264) break;
      int l = cc / 66;
      int idx0 = (cc - l * 66) * 8;     // base pair-idx within l
      const float* base = cs + off[l];
      u16x8 o;
#pragma unroll
      for (int t = 0; t < 8; ++t) {
        int idx = idx0 + t;
        int q = tri_q(idx);
        int r = q + idx - q * (65 - q) / 2;
        float s = 0.f;
        for (int m = 0; m < nm[l]; ++m) s += base[m * 32 + q] * base[m * 32 + r];
        o[t] = f2h(s * cg[l]);
      }
      *reinterpret_cast<u16x8*>(&fh[(size_t)a * NF2 + l * 528 + idx0]) = o;
    }
  } else if (b < PB_W0) {
    // ---- W0' [p][fk][h] -> W0t [p][h][fk] fp16, fk = packed pair index ----
    int idx = b - PB_FEAT;              // 2112 = 8(n) x 66(k) x 4(p)
    int nx = idx & 7;
    int ky = (idx >> 3) % 66, p = (idx >> 3) / 66;
    int kt = ky * 32, nt = nx * 32;
    int lx = tid & 31, ly = tid >> 5;
    float (*t)[33] = (float(*)[33])shbuf;
    const float* src = W0 + (size_t)p * 4096 * HID;
#pragma unroll
    for (int i = 0; i < 4; ++i) {
      int fk = kt + ly + i * 8;         // flat packed idx in [0,2112)
      int l = fk / 528, li = fk - l * 528;
      int q = tri_q(li);
      int r = q + li - q * (65 - q) / 2;
      float v = src[(size_t)(l * 1024 + q * 32 + r) * HID + nt + lx];
      if (q < r) v += src[(size_t)(l * 1024 + r * 32 + q) * HID + nt + lx];
      t[ly + i * 8][lx] = v;
    }
    __syncthreads();
    ushort* dst = W0t + (size_t)p * HID * NF2;
#pragma unroll
    for (int i = 0; i < 4; ++i)
      dst[(size_t)(nt + ly + i * 8) * NF2 + kt + lx] = f2h(t[lx][ly + i * 8]);
  } else if (b < PB_W1) {
    int idx = b - PB_W0;
    int nx = idx & 7, ky = (idx >> 3) & 7, p = idx >> 6;
    int kt = ky * 32, nt = nx * 32;
    int lx = tid & 31, ly = tid >> 5;
    float (*t)[33] = (float(*)[33])shbuf;
    const float* src = W1 + (size_t)p * HID * HID;
#pragma unroll
    for (int i = 0; i < 4; ++i)
      t[ly + i * 8][lx] = src[(size_t)(kt + ly + i * 8) * HID + nt + lx];
    __syncthreads();
    ushort* dst = W1t + (size_t)p * HID * HID;
#pragma unroll
    for (int i = 0; i < 4; ++i)
      dst[(size_t)(nt + ly + i * 8) * HID + kt + lx] = f2h(t[lx][ly + i * 8]);
  } else if (b < PB_ZERO) {
    // ---- zero fh rows [10000,10240): 240*2112 = 506880 ushorts ----
    int idx = b - PB_W1;
    size_t e = (size_t)idx * 2048 + tid * 8;
    if (e < (size_t)240 * NF2) {
      u16x8 z = (u16x8){0, 0, 0, 0, 0, 0, 0, 0};
      *reinterpret_cast<u16x8*>(&fh[(size_t)N_ATOMS * NF2 + e]) = z;
    }
  } else {
    if (tid < NSTRUCT) out[tid] = 0.f;
  }
}

// ---------------- Kernel B: fp16 MFMA GEMM0, 128x128, BK=32, K=2112 --------
// Same R8 structure: conflict-free interleaved-XOR LDS, XCD remap.
__global__ __launch_bounds__(256) void gemm0_mfma(
    const ushort* __restrict__ fh, const ushort* __restrict__ W0t,
    const float* __restrict__ combW, const int* __restrict__ species,
    ushort* __restrict__ h0f) {
  __shared__ ushort As[64 * 64];   // 8KB
  __shared__ ushort Bs[64 * 64];   // 8KB
  int tid = threadIdx.x;
  int linear = blockIdx.y * 8 + blockIdx.x;
  int xc = linear & 7, sq = linear >> 3;
  int bm = ((sq >> 3) * 8 + xc) * 128;   // m-tile
  int bn = (sq & 7) * 128;               // n-tile
  int wid = tid >> 6, lane = tid & 63;
  int wm = (wid >> 1) * 64, wn = (wid & 1) * 64;
  int mh = wid >> 1, nh = wid & 1;

  int pr = tid >> 3, pc = tid & 7;
  int lg = pc ^ (pr & 7);
  int mhalf = lg >> 2, kc = lg & 3;
  const ushort* gaA1 = fh  + ((size_t)(bm + pr + 64 * mhalf) * NF2 + kc * 8);
  const ushort* gaA2 = gaA1 + (size_t)32 * NF2;
  const ushort* gaB1 = W0t + ((size_t)(bn + pr + 64 * mhalf) * NF2 + kc * 8);
  const ushort* gaB2 = gaB1 + (size_t)32 * NF2;
  ushort* lA = As + tid * 8;
  ushort* lB = Bs + tid * 8;

  f32x4 acc[4][4];
#pragma unroll
  for (int i = 0; i < 4; ++i)
#pragma unroll
    for (int j = 0; j < 4; ++j) acc[i][j] = (f32x4){0.f, 0.f, 0.f, 0.f};

  int mrow = lane & 15;
  int h7 = mrow & 7;
  int qv = lane >> 4;
  int pcA = ((mh << 2) | qv) ^ h7;
  int pcB = ((nh << 2) | qv) ^ h7;

  for (int k0 = 0; k0 < NF2; k0 += 32) {
    glds16(gaA1 + k0, lA);
    glds16(gaA2 + k0, lA + 2048);
    glds16(gaB1 + k0, lB);
    glds16(gaB2 + k0, lB + 2048);
    __syncthreads();

    f16x8 af[4], bf[4];
#pragma unroll
    for (int i = 0; i < 4; ++i) {
      af[i] = *reinterpret_cast<const f16x8*>(&As[(i * 16 + mrow) * 64 + pcA * 8]);
      bf[i] = *reinterpret_cast<const f16x8*>(&Bs[(i * 16 + mrow) * 64 + pcB * 8]);
    }
#pragma unroll
    for (int i = 0; i < 4; ++i)
#pragma unroll
      for (int j = 0; j < 4; ++j)
        acc[i][j] = __builtin_amdgcn_mfma_f32_16x16x32_f16(af[i], bf[j], acc[i][j], 0, 0, 0);
    __syncthreads();
  }

  int p = bn >> 8;
  int col = lane & 15, rbase = (lane >> 4) * 4;
#pragma unroll
  for (int i = 0; i < 4; ++i) {
#pragma unroll
    for (int r = 0; r < 4; ++r) {
      int m = bm + wm + i * 16 + rbase + r;
      bool live = (m < N_ATOMS);
      float pw = live ? combW[p * NS + species[m]] : 0.f;
#pragma unroll
      for (int j = 0; j < 4; ++j) {
        int n = bn + wn + j * 16 + col;
        float v = live ? silu(pw * acc[i][j][r]) : 0.f;
        h0f[(size_t)m * 1024 + n] = f2h(v);
      }
    }
  }
}

// ---------------- Kernel C: layer-1 MFMA, whole-A-tile staged once ---------
__global__ __launch_bounds__(256) void mlp1_mfma(
    const ushort* __restrict__ h0f, const ushort* __restrict__ W1t,
    const float* __restrict__ W2, const int* __restrict__ sid,
    float* __restrict__ out) {
  __shared__ ushort As[64 * 256];   // 32KB
  __shared__ float sout[NSTRUCT];
  int tid = threadIdx.x;
  int linear = blockIdx.x;            // 0..2559
  int xc = linear & 7, s = linear >> 3;      // s in [0,320)
  int nidx = s & 15, t = s >> 4;             // t in [0,20)
  int bm = ((t >> 1) * 8 + xc) * 128 + (t & 1) * 64;   // 64-row tile
  int bn = nidx * 64;
  int p  = bn >> 8;
  int wid = tid >> 6, lane = tid & 63;
  int wm = (wid >> 1) * 32;
  int wn = (wid & 1) * 32;

  if (tid < NSTRUCT) sout[tid] = 0.f;

  int mrow = lane & 15;
  int qv = lane >> 4;

#pragma unroll
  for (int s8 = 0; s8 < 8; ++s8) {
    int d = s8 * 256 + tid;
    int r = d >> 5, pcs = d & 31;
    int lc = pcs ^ (r & 7);
    glds16(h0f + (size_t)(bm + r) * 1024 + p * 256 + lc * 8, As + d * 8);
  }

  const ushort* wb = W1t + (size_t)p * HID * HID;
  f16x8 breg[2][8];
#pragma unroll
  for (int j = 0; j < 2; ++j) {
    const ushort* row = wb + (size_t)((bn & 255) + wn + j * 16 + mrow) * 256 + qv * 8;
#pragma unroll
    for (int ki = 0; ki < 8; ++ki)
      breg[j][ki] = *reinterpret_cast<const f16x8*>(row + ki * 32);
  }

  __syncthreads();   // drains glds16 + sout init visible

  f32x4 acc[2][2];
#pragma unroll
  for (int i = 0; i < 2; ++i)
#pragma unroll
    for (int j = 0; j < 2; ++j) acc[i][j] = (f32x4){0.f, 0.f, 0.f, 0.f};

  int h7 = mrow & 7;
#pragma unroll
  for (int ki = 0; ki < 8; ++ki) {
    f16x8 af[2];
#pragma unroll
    for (int i = 0; i < 2; ++i) {
      int row = wm + i * 16 + mrow;
      int pc2 = (ki * 4 + qv) ^ h7;
      af[i] = *reinterpret_cast<const f16x8*>(&As[row * 256 + pc2 * 8]);
    }
#pragma unroll
    for (int i = 0; i < 2; ++i)
#pragma unroll
      for (int j = 0; j < 2; ++j)
        acc[i][j] = __builtin_amdgcn_mfma_f32_16x16x32_f16(af[i], breg[j][ki], acc[i][j], 0, 0, 0);
  }

  int col = lane & 15, quad = lane >> 4;
  float w2j0 = W2[bn + wn + col];
  float w2j1 = W2[bn + wn + 16 + col];
#pragma unroll
  for (int i = 0; i < 2; ++i) {
#pragma unroll
    for (int r = 0; r < 4; ++r) {
      float v = silu(acc[i][0][r]) * w2j0 + silu(acc[i][1][r]) * w2j1;
      v += __shfl_xor(v, 1, 64);
      v += __shfl_xor(v, 2, 64);
      v += __shfl_xor(v, 4, 64);
      v += __shfl_xor(v, 8, 64);
      if (col == 0) {
        int m = bm + wm + i * 16 + quad * 4 + r;
        if (m < N_ATOMS) atomicAdd(&sout[sid[m]], v);
      }
    }
  }
  __syncthreads();
  if (tid < NSTRUCT) {
    float v = sout[tid];
    if (v != 0.f) atomicAdd(&out[tid], v);
  }
}

extern "C" void kernel_launch(void* const* d_in, const int* in_sizes, int n_in,
                              void* d_out, int out_size, void* d_ws, size_t ws_size,
                              hipStream_t stream) {
  const float* c0      = (const float*)d_in[0];
  const float* c1      = (const float*)d_in[1];
  const float* c2      = (const float*)d_in[2];
  const float* c3      = (const float*)d_in[3];
  const int*   species = (const int*)d_in[4];
  const int*   sid     = (const int*)d_in[5];
  const float* combW   = (const float*)d_in[6];
  const float* W0      = (const float*)d_in[7];
  const float* W1      = (const float*)d_in[8];
  const float* W2      = (const float*)d_in[9];
  float*       out     = (float*)d_out;

  // ws: fh 43.2MB | W0t 4.3MB | W1t 0.5MB | h0f 21MB = ~69MB
  ushort* fh  = (ushort*)d_ws;
  ushort* W0t = fh  + (size_t)APAD * NF2;
  ushort* W1t = W0t + (size_t)NP * HID * NF2;
  ushort* h0f = W1t + (size_t)NP * HID * HID;

  prep_kernel<<<PB_TOTAL, 256, 0, stream>>>(c0, c1, c2, c3, W0, W1,
                                            fh, W0t, W1t, out);

  dim3 g2(8, APAD / 128);    // 8 n-tiles x 80 remapped slots
  gemm0_mfma<<<g2, 256, 0, stream>>>(fh, W0t, combW, species, h0f);

  mlp1_mfma<<<2560, 256, 0, stream>>>(h0f, W1t, W2, sid, out);
}

// Round 16
// 216.932 us; speedup vs baseline: 1.2105x; 1.0556x over previous
//
#include <hip/hip_runtime.h>
#include <hip/hip_bf16.h>
#include <cstdint>
#include <cstddef>

#define N_ATOMS 10000
#define NSTRUCT 100
#define NP 4
#define NS 4
#define NF2 2560      // 4 l x 640 block-aligned symmetric-packed features
#define HID 256
#define APAD 10240    // 80 tiles of 128

// prep-kernel block ranges
#define PB_FEAT  10000                    // [0,10000): power spectrum
#define PB_W0    (PB_FEAT + 2560)         // w0cvt: 8(n) x 80(k) x 4(p)
#define PB_W1    (PB_W0 + 256)            // w1cvt: 8 x 8 x 4
#define PB_ZERO  (PB_W1 + 300)            // fh tail rows 10000..10239
#define PB_TOTAL (PB_ZERO + 1)            // + out zero

typedef __attribute__((ext_vector_type(8))) _Float16 f16x8;
typedef __attribute__((ext_vector_type(8))) ushort u16x8;
typedef __attribute__((ext_vector_type(4))) float f32x4;

__device__ __forceinline__ float silu(float x) {
  return x / (1.f + __expf(-x));
}
__device__ __forceinline__ ushort f2h(float x) {
  _Float16 h = (_Float16)x;
  return *reinterpret_cast<ushort*>(&h);
}
// chunk c in [0,80) -> (row q, r-block b). Row q owns blocks q>>3 .. 3.
__device__ __forceinline__ void cdec(int c, int& q, int& b) {
  if (c < 32)      { q = c >> 2; b = c & 3; }
  else if (c < 56) { int x = c - 32; int j = (x * 171) >> 9; q = 8 + j; b = 1 + (x - j * 3); }
  else if (c < 72) { int x = c - 56; q = 16 + (x >> 1); b = 2 + (x & 1); }
  else             { q = 24 + (c - 72); b = 3; }
}

typedef __attribute__((address_space(3))) uint32_t lds_u32;
typedef const __attribute__((address_space(1))) uint32_t glb_u32;
__device__ __forceinline__ void glds16(const ushort* g, ushort* l) {
  __builtin_amdgcn_global_load_lds((glb_u32*)g, (lds_u32*)l, 16, 0, 0);
}

// ---------------- Kernel P: fused prep -------------------------------------
__global__ __launch_bounds__(256) void prep_kernel(
    const float* __restrict__ c0, const float* __restrict__ c1,
    const float* __restrict__ c2, const float* __restrict__ c3,
    const float* __restrict__ W0, const float* __restrict__ W1,
    ushort* __restrict__ fh, ushort* __restrict__ W0t,
    ushort* __restrict__ W1t, float* __restrict__ out) {
  __shared__ float shbuf[32 * 33];
  int b = blockIdx.x;
  int tid = threadIdx.x;

  if (b < PB_FEAT) {
    // ---- block-aligned packed power spectrum -> fp16 (vectorized) ----
    int a = b;
    float* cs = shbuf;
    for (int e = tid; e < 512; e += 256) {
      float v;
      if (e < 32)       v = c0[a * 32  + e];
      else if (e < 128) v = c1[a * 96  + (e - 32)];
      else if (e < 288) v = c2[a * 160 + (e - 128)];
      else              v = c3[a * 224 + (e - 288)];
      cs[e] = v;
    }
    __syncthreads();
    const float cg[4]  = {1.0f, 0.5773502691896258f, 0.4472135954999579f, 0.3779644730092272f};
    const int  off[4]  = {0, 32, 128, 288};
    const int  nm[4]   = {1, 3, 5, 7};
#pragma unroll
    for (int it = 0; it < 2; ++it) {
      int cc = tid + it * 256;          // chunk in [0,320)
      if (cc >= 320) break;
      int l = cc / 80, c = cc - l * 80;
      int q, bb; cdec(c, q, bb);
      int rb = bb * 8;
      const float* base = cs + off[l];
      float s[8] = {0.f, 0.f, 0.f, 0.f, 0.f, 0.f, 0.f, 0.f};
      for (int m = 0; m < nm[l]; ++m) {
        float bq = base[m * 32 + q];                     // wave-broadcast
        float4 v0 = *reinterpret_cast<const float4*>(&base[m * 32 + rb]);
        float4 v1 = *reinterpret_cast<const float4*>(&base[m * 32 + rb + 4]);
        s[0] += bq * v0.x; s[1] += bq * v0.y; s[2] += bq * v0.z; s[3] += bq * v0.w;
        s[4] += bq * v1.x; s[5] += bq * v1.y; s[6] += bq * v1.z; s[7] += bq * v1.w;
      }
      u16x8 o;
#pragma unroll
      for (int t = 0; t < 8; ++t) o[t] = f2h(s[t] * cg[l]);
      *reinterpret_cast<u16x8*>(&fh[(size_t)a * NF2 + cc * 8]) = o;   // l*640+c*8 == cc*8
    }
  } else if (b < PB_W0) {
    // ---- W0' fold -> W0t [p][h][fk] fp16; fk = block-aligned packed idx ----
    int idx = b - PB_FEAT;              // 2560 = 8(n) x 320(k-tile x p)
    int nx = idx & 7;
    int rest = idx >> 3;                // [0,320)
    int ky = rest % 80, p = rest / 80;
    int kt = ky * 32, nt = nx * 32;
    int lx = tid & 31, ly = tid >> 5;
    float (*t)[33] = (float(*)[33])shbuf;
    const float* src = W0 + (size_t)p * 4096 * HID;
#pragma unroll
    for (int i = 0; i < 4; ++i) {
      int kf = kt + ly + i * 8;         // flat packed idx [0,2560)
      int l = kf / 640, w = kf - l * 640;
      int c = w >> 3, s = w & 7;
      int q, bb; cdec(c, q, bb);
      int r = bb * 8 + s;
      float v = 0.f;
      if (r >= q) {
        v = src[(size_t)(l * 1024 + q * 32 + r) * HID + nt + lx];
        if (r > q) v += src[(size_t)(l * 1024 + r * 32 + q) * HID + nt + lx];
      }
      t[ly + i * 8][lx] = v;
    }
    __syncthreads();
    ushort* dst = W0t + (size_t)p * HID * NF2;
#pragma unroll
    for (int i = 0; i < 4; ++i)
      dst[(size_t)(nt + ly + i * 8) * NF2 + kt + lx] = f2h(t[lx][ly + i * 8]);
  } else if (b < PB_W1) {
    int idx = b - PB_W0;
    int nx = idx & 7, ky = (idx >> 3) & 7, p = idx >> 6;
    int kt = ky * 32, nt = nx * 32;
    int lx = tid & 31, ly = tid >> 5;
    float (*t)[33] = (float(*)[33])shbuf;
    const float* src = W1 + (size_t)p * HID * HID;
#pragma unroll
    for (int i = 0; i < 4; ++i)
      t[ly + i * 8][lx] = src[(size_t)(kt + ly + i * 8) * HID + nt + lx];
    __syncthreads();
    ushort* dst = W1t + (size_t)p * HID * HID;
#pragma unroll
    for (int i = 0; i < 4; ++i)
      dst[(size_t)(nt + ly + i * 8) * HID + kt + lx] = f2h(t[lx][ly + i * 8]);
  } else if (b < PB_ZERO) {
    // ---- zero fh rows [10000,10240): 240*2560 = 614400 ushorts ----
    int idx = b - PB_W1;                // 300 blocks x 2048
    size_t e = (size_t)idx * 2048 + tid * 8;
    u16x8 z = (u16x8){0, 0, 0, 0, 0, 0, 0, 0};
    *reinterpret_cast<u16x8*>(&fh[(size_t)N_ATOMS * NF2 + e]) = z;
  } else {
    if (tid < NSTRUCT) out[tid] = 0.f;
  }
}

// ---------------- Kernel B: fp16 MFMA GEMM0, 128x128, BK=32, K=2560 --------
// R8 structure: conflict-free interleaved-XOR LDS, XCD remap.
__global__ __launch_bounds__(256) void gemm0_mfma(
    const ushort* __restrict__ fh, const ushort* __restrict__ W0t,
    const float* __restrict__ combW, const int* __restrict__ species,
    ushort* __restrict__ h0f) {
  __shared__ ushort As[64 * 64];   // 8KB
  __shared__ ushort Bs[64 * 64];   // 8KB
  int tid = threadIdx.x;
  int linear = blockIdx.y * 8 + blockIdx.x;
  int xc = linear & 7, sq = linear >> 3;
  int bm = ((sq >> 3) * 8 + xc) * 128;   // m-tile
  int bn = (sq & 7) * 128;               // n-tile
  int wid = tid >> 6, lane = tid & 63;
  int wm = (wid >> 1) * 64, wn = (wid & 1) * 64;
  int mh = wid >> 1, nh = wid & 1;

  int pr = tid >> 3, pc = tid & 7;
  int lg = pc ^ (pr & 7);
  int mhalf = lg >> 2, kc = lg & 3;
  const ushort* gaA1 = fh  + ((size_t)(bm + pr + 64 * mhalf) * NF2 + kc * 8);
  const ushort* gaA2 = gaA1 + (size_t)32 * NF2;
  const ushort* gaB1 = W0t + ((size_t)(bn + pr + 64 * mhalf) * NF2 + kc * 8);
  const ushort* gaB2 = gaB1 + (size_t)32 * NF2;
  ushort* lA = As + tid * 8;
  ushort* lB = Bs + tid * 8;

  f32x4 acc[4][4];
#pragma unroll
  for (int i = 0; i < 4; ++i)
#pragma unroll
    for (int j = 0; j < 4; ++j) acc[i][j] = (f32x4){0.f, 0.f, 0.f, 0.f};

  int mrow = lane & 15;
  int h7 = mrow & 7;
  int qv = lane >> 4;
  int pcA = ((mh << 2) | qv) ^ h7;
  int pcB = ((nh << 2) | qv) ^ h7;

  for (int k0 = 0; k0 < NF2; k0 += 32) {
    glds16(gaA1 + k0, lA);
    glds16(gaA2 + k0, lA + 2048);
    glds16(gaB1 + k0, lB);
    glds16(gaB2 + k0, lB + 2048);
    __syncthreads();

    f16x8 af[4], bf[4];
#pragma unroll
    for (int i = 0; i < 4; ++i) {
      af[i] = *reinterpret_cast<const f16x8*>(&As[(i * 16 + mrow) * 64 + pcA * 8]);
      bf[i] = *reinterpret_cast<const f16x8*>(&Bs[(i * 16 + mrow) * 64 + pcB * 8]);
    }
#pragma unroll
    for (int i = 0; i < 4; ++i)
#pragma unroll
      for (int j = 0; j < 4; ++j)
        acc[i][j] = __builtin_amdgcn_mfma_f32_16x16x32_f16(af[i], bf[j], acc[i][j], 0, 0, 0);
    __syncthreads();
  }

  int p = bn >> 8;
  int col = lane & 15, rbase = (lane >> 4) * 4;
#pragma unroll
  for (int i = 0; i < 4; ++i) {
#pragma unroll
    for (int r = 0; r < 4; ++r) {
      int m = bm + wm + i * 16 + rbase + r;
      bool live = (m < N_ATOMS);
      float pw = live ? combW[p * NS + species[m]] : 0.f;
#pragma unroll
      for (int j = 0; j < 4; ++j) {
        int n = bn + wn + j * 16 + col;
        float v = live ? silu(pw * acc[i][j][r]) : 0.f;
        h0f[(size_t)m * 1024 + n] = f2h(v);
      }
    }
  }
}

// ---------------- Kernel C: layer-1 MFMA, whole-A-tile staged once ---------
__global__ __launch_bounds__(256) void mlp1_mfma(
    const ushort* __restrict__ h0f, const ushort* __restrict__ W1t,
    const float* __restrict__ W2, const int* __restrict__ sid,
    float* __restrict__ out) {
  __shared__ ushort As[64 * 256];   // 32KB
  __shared__ float sout[NSTRUCT];
  int tid = threadIdx.x;
  int linear = blockIdx.x;            // 0..2559
  int xc = linear & 7, s = linear >> 3;      // s in [0,320)
  int nidx = s & 15, t = s >> 4;             // t in [0,20)
  int bm = ((t >> 1) * 8 + xc) * 128 + (t & 1) * 64;   // 64-row tile
  int bn = nidx * 64;
  int p  = bn >> 8;
  int wid = tid >> 6, lane = tid & 63;
  int wm = (wid >> 1) * 32;
  int wn = (wid & 1) * 32;

  if (tid < NSTRUCT) sout[tid] = 0.f;

  int mrow = lane & 15;
  int qv = lane >> 4;

#pragma unroll
  for (int s8 = 0; s8 < 8; ++s8) {
    int d = s8 * 256 + tid;
    int r = d >> 5, pcs = d & 31;
    int lc = pcs ^ (r & 7);
    glds16(h0f + (size_t)(bm + r) * 1024 + p * 256 + lc * 8, As + d * 8);
  }

  const ushort* wb = W1t + (size_t)p * HID * HID;
  f16x8 breg[2][8];
#pragma unroll
  for (int j = 0; j < 2; ++j) {
    const ushort* row = wb + (size_t)((bn & 255) + wn + j * 16 + mrow) * 256 + qv * 8;
#pragma unroll
    for (int ki = 0; ki < 8; ++ki)
      breg[j][ki] = *reinterpret_cast<const f16x8*>(row + ki * 32);
  }

  __syncthreads();   // drains glds16 + sout init visible

  f32x4 acc[2][2];
#pragma unroll
  for (int i = 0; i < 2; ++i)
#pragma unroll
    for (int j = 0; j < 2; ++j) acc[i][j] = (f32x4){0.f, 0.f, 0.f, 0.f};

  int h7 = mrow & 7;
#pragma unroll
  for (int ki = 0; ki < 8; ++ki) {
    f16x8 af[2];
#pragma unroll
    for (int i = 0; i < 2; ++i) {
      int row = wm + i * 16 + mrow;
      int pc2 = (ki * 4 + qv) ^ h7;
      af[i] = *reinterpret_cast<const f16x8*>(&As[row * 256 + pc2 * 8]);
    }
#pragma unroll
    for (int i = 0; i < 2; ++i)
#pragma unroll
      for (int j = 0; j < 2; ++j)
        acc[i][j] = __builtin_amdgcn_mfma_f32_16x16x32_f16(af[i], breg[j][ki], acc[i][j], 0, 0, 0);
  }

  int col = lane & 15, quad = lane >> 4;
  float w2j0 = W2[bn + wn + col];
  float w2j1 = W2[bn + wn + 16 + col];
#pragma unroll
  for (int i = 0; i < 2; ++i) {
#pragma unroll
    for (int r = 0; r < 4; ++r) {
      float v = silu(acc[i][0][r]) * w2j0 + silu(acc[i][1][r]) * w2j1;
      v += __shfl_xor(v, 1, 64);
      v += __shfl_xor(v, 2, 64);
      v += __shfl_xor(v, 4, 64);
      v += __shfl_xor(v, 8, 64);
      if (col == 0) {
        int m = bm + wm + i * 16 + quad * 4 + r;
        if (m < N_ATOMS) atomicAdd(&sout[sid[m]], v);
      }
    }
  }
  __syncthreads();
  if (tid < NSTRUCT) {
    float v = sout[tid];
    if (v != 0.f) atomicAdd(&out[tid], v);
  }
}

extern "C" void kernel_launch(void* const* d_in, const int* in_sizes, int n_in,
                              void* d_out, int out_size, void* d_ws, size_t ws_size,
                              hipStream_t stream) {
  const float* c0      = (const float*)d_in[0];
  const float* c1      = (const float*)d_in[1];
  const float* c2      = (const float*)d_in[2];
  const float* c3      = (const float*)d_in[3];
  const int*   species = (const int*)d_in[4];
  const int*   sid     = (const int*)d_in[5];
  const float* combW   = (const float*)d_in[6];
  const float* W0      = (const float*)d_in[7];
  const float* W1      = (const float*)d_in[8];
  const float* W2      = (const float*)d_in[9];
  float*       out     = (float*)d_out;

  // ws: fh 52.4MB | W0t 5.2MB | W1t 0.5MB | h0f 21MB = ~79MB
  ushort* fh  = (ushort*)d_ws;
  ushort* W0t = fh  + (size_t)APAD * NF2;
  ushort* W1t = W0t + (size_t)NP * HID * NF2;
  ushort* h0f = W1t + (size_t)NP * HID * HID;

  prep_kernel<<<PB_TOTAL, 256, 0, stream>>>(c0, c1, c2, c3, W0, W1,
                                            fh, W0t, W1t, out);

  dim3 g2(8, APAD / 128);    // 8 n-tiles x 80 remapped slots
  gemm0_mfma<<<g2, 256, 0, stream>>>(fh, W0t, combW, species, h0f);

  mlp1_mfma<<<2560, 256, 0, stream>>>(h0f, W1t, W2, sid, out);
}

// Round 17
// 211.578 us; speedup vs baseline: 1.2412x; 1.0253x over previous
//
#include <hip/hip_runtime.h>
#include <hip/hip_bf16.h>
#include <cstdint>
#include <cstddef>

#define N_ATOMS 10000
#define NSTRUCT 100
#define NP 4
#define NS 4
#define NF2 2560      // 4 l x 640 block-aligned symmetric-packed features
#define HID 256
#define APAD 10240    // 80 tiles of 128

// prep-kernel block ranges
#define PB_FEAT  10000                    // [0,10000): power spectrum
#define PB_W0    (PB_FEAT + 2560)         // w0cvt: 8(n) x 80(k) x 4(p)
#define PB_W1    (PB_W0 + 256)            // w1cvt: 8 x 8 x 4
#define PB_ZERO  (PB_W1 + 300)            // fh tail rows 10000..10239
#define PB_TOTAL (PB_ZERO + 1)            // + out zero

typedef __attribute__((ext_vector_type(8))) _Float16 f16x8;
typedef __attribute__((ext_vector_type(8))) ushort u16x8;
typedef __attribute__((ext_vector_type(4))) float f32x4;

__device__ __forceinline__ float silu(float x) {
  return x / (1.f + __expf(-x));
}
__device__ __forceinline__ ushort f2h(float x) {
  _Float16 h = (_Float16)x;
  return *reinterpret_cast<ushort*>(&h);
}
// chunk c in [0,80) -> (row q, r-block b). Row q owns blocks q>>3 .. 3.
__device__ __forceinline__ void cdec(int c, int& q, int& b) {
  if (c < 32)      { q = c >> 2; b = c & 3; }
  else if (c < 56) { int x = c - 32; int j = (x * 171) >> 9; q = 8 + j; b = 1 + (x - j * 3); }
  else if (c < 72) { int x = c - 56; q = 16 + (x >> 1); b = 2 + (x & 1); }
  else             { q = 24 + (c - 72); b = 3; }
}

typedef __attribute__((address_space(3))) uint32_t lds_u32;
typedef const __attribute__((address_space(1))) uint32_t glb_u32;
__device__ __forceinline__ void glds16(const ushort* g, ushort* l) {
  __builtin_amdgcn_global_load_lds((glb_u32*)g, (lds_u32*)l, 16, 0, 0);
}

// ---------------- Kernel P: fused prep -------------------------------------
__global__ __launch_bounds__(256) void prep_kernel(
    const float* __restrict__ c0, const float* __restrict__ c1,
    const float* __restrict__ c2, const float* __restrict__ c3,
    const float* __restrict__ W0, const float* __restrict__ W1,
    ushort* __restrict__ fh, ushort* __restrict__ W0t,
    ushort* __restrict__ W1t, float* __restrict__ out) {
  __shared__ float shbuf[32 * 33];
  int b = blockIdx.x;
  int tid = threadIdx.x;

  if (b < PB_FEAT) {
    // ---- block-aligned packed power spectrum -> fp16 (vectorized) ----
    int a = b;
    float* cs = shbuf;
    for (int e = tid; e < 512; e += 256) {
      float v;
      if (e < 32)       v = c0[a * 32  + e];
      else if (e < 128) v = c1[a * 96  + (e - 32)];
      else if (e < 288) v = c2[a * 160 + (e - 128)];
      else              v = c3[a * 224 + (e - 288)];
      cs[e] = v;
    }
    __syncthreads();
    const float cg[4]  = {1.0f, 0.5773502691896258f, 0.4472135954999579f, 0.3779644730092272f};
    const int  off[4]  = {0, 32, 128, 288};
    const int  nm[4]   = {1, 3, 5, 7};
#pragma unroll
    for (int it = 0; it < 2; ++it) {
      int cc = tid + it * 256;          // chunk in [0,320)
      if (cc >= 320) break;
      int l = cc / 80, c = cc - l * 80;
      int q, bb; cdec(c, q, bb);
      int rb = bb * 8;
      const float* base = cs + off[l];
      float s[8] = {0.f, 0.f, 0.f, 0.f, 0.f, 0.f, 0.f, 0.f};
      for (int m = 0; m < nm[l]; ++m) {
        float bq = base[m * 32 + q];                     // wave-broadcast
        float4 v0 = *reinterpret_cast<const float4*>(&base[m * 32 + rb]);
        float4 v1 = *reinterpret_cast<const float4*>(&base[m * 32 + rb + 4]);
        s[0] += bq * v0.x; s[1] += bq * v0.y; s[2] += bq * v0.z; s[3] += bq * v0.w;
        s[4] += bq * v1.x; s[5] += bq * v1.y; s[6] += bq * v1.z; s[7] += bq * v1.w;
      }
      u16x8 o;
#pragma unroll
      for (int t = 0; t < 8; ++t) o[t] = f2h(s[t] * cg[l]);
      *reinterpret_cast<u16x8*>(&fh[(size_t)a * NF2 + cc * 8]) = o;
    }
  } else if (b < PB_W0) {
    // ---- W0' fold -> W0t [p][h][fk] fp16 ----
    int idx = b - PB_FEAT;
    int nx = idx & 7;
    int rest = idx >> 3;
    int ky = rest % 80, p = rest / 80;
    int kt = ky * 32, nt = nx * 32;
    int lx = tid & 31, ly = tid >> 5;
    float (*t)[33] = (float(*)[33])shbuf;
    const float* src = W0 + (size_t)p * 4096 * HID;
#pragma unroll
    for (int i = 0; i < 4; ++i) {
      int kf = kt + ly + i * 8;
      int l = kf / 640, w = kf - l * 640;
      int c = w >> 3, s = w & 7;
      int q, bb; cdec(c, q, bb);
      int r = bb * 8 + s;
      float v = 0.f;
      if (r >= q) {
        v = src[(size_t)(l * 1024 + q * 32 + r) * HID + nt + lx];
        if (r > q) v += src[(size_t)(l * 1024 + r * 32 + q) * HID + nt + lx];
      }
      t[ly + i * 8][lx] = v;
    }
    __syncthreads();
    ushort* dst = W0t + (size_t)p * HID * NF2;
#pragma unroll
    for (int i = 0; i < 4; ++i)
      dst[(size_t)(nt + ly + i * 8) * NF2 + kt + lx] = f2h(t[lx][ly + i * 8]);
  } else if (b < PB_W1) {
    int idx = b - PB_W0;
    int nx = idx & 7, ky = (idx >> 3) & 7, p = idx >> 6;
    int kt = ky * 32, nt = nx * 32;
    int lx = tid & 31, ly = tid >> 5;
    float (*t)[33] = (float(*)[33])shbuf;
    const float* src = W1 + (size_t)p * HID * HID;
#pragma unroll
    for (int i = 0; i < 4; ++i)
      t[ly + i * 8][lx] = src[(size_t)(kt + ly + i * 8) * HID + nt + lx];
    __syncthreads();
    ushort* dst = W1t + (size_t)p * HID * HID;
#pragma unroll
    for (int i = 0; i < 4; ++i)
      dst[(size_t)(nt + ly + i * 8) * HID + kt + lx] = f2h(t[lx][ly + i * 8]);
  } else if (b < PB_ZERO) {
    int idx = b - PB_W1;
    size_t e = (size_t)idx * 2048 + tid * 8;
    u16x8 z = (u16x8){0, 0, 0, 0, 0, 0, 0, 0};
    *reinterpret_cast<u16x8*>(&fh[(size_t)N_ATOMS * NF2 + e]) = z;
  } else {
    if (tid < NSTRUCT) out[tid] = 0.f;
  }
}

// ---------------- Kernel B: fp16 MFMA GEMM0, 128x128, BK=32, K=2560 --------
__global__ __launch_bounds__(256) void gemm0_mfma(
    const ushort* __restrict__ fh, const ushort* __restrict__ W0t,
    const float* __restrict__ combW, const int* __restrict__ species,
    ushort* __restrict__ h0f) {
  __shared__ ushort As[64 * 64];   // 8KB
  __shared__ ushort Bs[64 * 64];   // 8KB
  int tid = threadIdx.x;
  int linear = blockIdx.y * 8 + blockIdx.x;
  int xc = linear & 7, sq = linear >> 3;
  int bm = ((sq >> 3) * 8 + xc) * 128;   // m-tile
  int bn = (sq & 7) * 128;               // n-tile
  int wid = tid >> 6, lane = tid & 63;
  int wm = (wid >> 1) * 64, wn = (wid & 1) * 64;
  int mh = wid >> 1, nh = wid & 1;

  int pr = tid >> 3, pc = tid & 7;
  int lg = pc ^ (pr & 7);
  int mhalf = lg >> 2, kc = lg & 3;
  const ushort* gaA1 = fh  + ((size_t)(bm + pr + 64 * mhalf) * NF2 + kc * 8);
  const ushort* gaA2 = gaA1 + (size_t)32 * NF2;
  const ushort* gaB1 = W0t + ((size_t)(bn + pr + 64 * mhalf) * NF2 + kc * 8);
  const ushort* gaB2 = gaB1 + (size_t)32 * NF2;
  ushort* lA = As + tid * 8;
  ushort* lB = Bs + tid * 8;

  f32x4 acc[4][4];
#pragma unroll
  for (int i = 0; i < 4; ++i)
#pragma unroll
    for (int j = 0; j < 4; ++j) acc[i][j] = (f32x4){0.f, 0.f, 0.f, 0.f};

  int mrow = lane & 15;
  int h7 = mrow & 7;
  int qv = lane >> 4;
  int pcA = ((mh << 2) | qv) ^ h7;
  int pcB = ((nh << 2) | qv) ^ h7;

  for (int k0 = 0; k0 < NF2; k0 += 32) {
    glds16(gaA1 + k0, lA);
    glds16(gaA2 + k0, lA + 2048);
    glds16(gaB1 + k0, lB);
    glds16(gaB2 + k0, lB + 2048);
    __syncthreads();

    f16x8 af[4], bf[4];
#pragma unroll
    for (int i = 0; i < 4; ++i) {
      af[i] = *reinterpret_cast<const f16x8*>(&As[(i * 16 + mrow) * 64 + pcA * 8]);
      bf[i] = *reinterpret_cast<const f16x8*>(&Bs[(i * 16 + mrow) * 64 + pcB * 8]);
    }
#pragma unroll
    for (int i = 0; i < 4; ++i)
#pragma unroll
      for (int j = 0; j < 4; ++j)
        acc[i][j] = __builtin_amdgcn_mfma_f32_16x16x32_f16(af[i], bf[j], acc[i][j], 0, 0, 0);
    __syncthreads();
  }

  int p = bn >> 8;
  int col = lane & 15, rbase = (lane >> 4) * 4;
#pragma unroll
  for (int i = 0; i < 4; ++i) {
#pragma unroll
    for (int r = 0; r < 4; ++r) {
      int m = bm + wm + i * 16 + rbase + r;
      bool live = (m < N_ATOMS);
      float pw = live ? combW[p * NS + species[m]] : 0.f;
#pragma unroll
      for (int j = 0; j < 4; ++j) {
        int n = bn + wn + j * 16 + col;
        float v = live ? silu(pw * acc[i][j][r]) : 0.f;
        h0f[(size_t)m * 1024 + n] = f2h(v);
      }
    }
  }
}

// ---------------- Kernel C: layer-1 MFMA, 64m x 256n(one p) per block ------
// A (64x256, 32KB) staged ONCE, shared by 4 waves; wave w owns n-quarter
// [w*64, w*64+64). B fragments (4 j x 8 ki) preloaded from L2-hot W1t.
// h0f read exactly once across the grid (21 MB). 640 blocks, XCD-mapped.
__global__ __launch_bounds__(256) void mlp1_mfma(
    const ushort* __restrict__ h0f, const ushort* __restrict__ W1t,
    const float* __restrict__ W2, const int* __restrict__ sid,
    float* __restrict__ out) {
  __shared__ ushort As[64 * 256];   // 32KB
  __shared__ float sout[NSTRUCT];
  int tid = threadIdx.x;
  int linear = blockIdx.x;                   // 0..639
  int xc = linear & 7, s = linear >> 3;      // s in [0,80)
  int p = s & 3, t = s >> 2;                 // t in [0,20)
  int bm = ((t >> 1) * 8 + xc) * 128 + (t & 1) * 64;   // 64-row tile
  int wid = tid >> 6, lane = tid & 63;
  int wn = wid * 64;                         // wave's n-quarter within p

  if (tid < NSTRUCT) sout[tid] = 0.f;

  int mrow = lane & 15;
  int qv = lane >> 4;
  int h7 = mrow & 7;

  // stage A: 64 rows x 256 k, chunk XOR by row&7 (conflict-free geometry)
#pragma unroll
  for (int s8 = 0; s8 < 8; ++s8) {
    int d = s8 * 256 + tid;
    int r = d >> 5, pcs = d & 31;
    int lc = pcs ^ (r & 7);
    glds16(h0f + (size_t)(bm + r) * 1024 + p * 256 + lc * 8, As + d * 8);
  }

  // B fragments: n = wn + j*16 + mrow, k = ki*32 + qv*8 .. +8
  const ushort* wb = W1t + (size_t)p * HID * HID;
  f16x8 breg[4][8];
#pragma unroll
  for (int j = 0; j < 4; ++j) {
    const ushort* row = wb + (size_t)(wn + j * 16 + mrow) * 256 + qv * 8;
#pragma unroll
    for (int ki = 0; ki < 8; ++ki)
      breg[j][ki] = *reinterpret_cast<const f16x8*>(row + ki * 32);
  }

  __syncthreads();   // drains glds16 + sout init visible

  f32x4 acc[4][4];
#pragma unroll
  for (int i = 0; i < 4; ++i)
#pragma unroll
    for (int j = 0; j < 4; ++j) acc[i][j] = (f32x4){0.f, 0.f, 0.f, 0.f};

#pragma unroll
  for (int ki = 0; ki < 8; ++ki) {
    f16x8 af[4];
#pragma unroll
    for (int i = 0; i < 4; ++i) {
      int row = i * 16 + mrow;
      int pc2 = (ki * 4 + qv) ^ h7;
      af[i] = *reinterpret_cast<const f16x8*>(&As[row * 256 + pc2 * 8]);
    }
#pragma unroll
    for (int i = 0; i < 4; ++i)
#pragma unroll
      for (int j = 0; j < 4; ++j)
        acc[i][j] = __builtin_amdgcn_mfma_f32_16x16x32_f16(af[i], breg[j][ki], acc[i][j], 0, 0, 0);
  }

  // fused layer-2 + segment-sum epilogue (LDS-staged)
  int col = lane & 15, quad = lane >> 4;
  float w2j[4];
#pragma unroll
  for (int j = 0; j < 4; ++j) w2j[j] = W2[p * 256 + wn + j * 16 + col];
#pragma unroll
  for (int i = 0; i < 4; ++i) {
#pragma unroll
    for (int r = 0; r < 4; ++r) {
      float v = silu(acc[i][0][r]) * w2j[0] + silu(acc[i][1][r]) * w2j[1]
              + silu(acc[i][2][r]) * w2j[2] + silu(acc[i][3][r]) * w2j[3];
      v += __shfl_xor(v, 1, 64);
      v += __shfl_xor(v, 2, 64);
      v += __shfl_xor(v, 4, 64);
      v += __shfl_xor(v, 8, 64);
      if (col == 0) {
        int m = bm + i * 16 + quad * 4 + r;
        if (m < N_ATOMS) atomicAdd(&sout[sid[m]], v);
      }
    }
  }
  __syncthreads();
  if (tid < NSTRUCT) {
    float v = sout[tid];
    if (v != 0.f) atomicAdd(&out[tid], v);
  }
}

extern "C" void kernel_launch(void* const* d_in, const int* in_sizes, int n_in,
                              void* d_out, int out_size, void* d_ws, size_t ws_size,
                              hipStream_t stream) {
  const float* c0      = (const float*)d_in[0];
  const float* c1      = (const float*)d_in[1];
  const float* c2      = (const float*)d_in[2];
  const float* c3      = (const float*)d_in[3];
  const int*   species = (const int*)d_in[4];
  const int*   sid     = (const int*)d_in[5];
  const float* combW   = (const float*)d_in[6];
  const float* W0      = (const float*)d_in[7];
  const float* W1      = (const float*)d_in[8];
  const float* W2      = (const float*)d_in[9];
  float*       out     = (float*)d_out;

  // ws: fh 52.4MB | W0t 5.2MB | W1t 0.5MB | h0f 21MB = ~79MB
  ushort* fh  = (ushort*)d_ws;
  ushort* W0t = fh  + (size_t)APAD * NF2;
  ushort* W1t = W0t + (size_t)NP * HID * NF2;
  ushort* h0f = W1t + (size_t)NP * HID * HID;

  prep_kernel<<<PB_TOTAL, 256, 0, stream>>>(c0, c1, c2, c3, W0, W1,
                                            fh, W0t, W1t, out);

  dim3 g2(8, APAD / 128);    // 8 n-tiles x 80 remapped slots
  gemm0_mfma<<<g2, 256, 0, stream>>>(fh, W0t, combW, species, h0f);

  mlp1_mfma<<<640, 256, 0, stream>>>(h0f, W1t, W2, sid, out);
}

// Round 18
// 206.330 us; speedup vs baseline: 1.2727x; 1.0254x over previous
//
#include <hip/hip_runtime.h>
#include <hip/hip_bf16.h>
#include <cstdint>
#include <cstddef>

#define N_ATOMS 10000
#define NSTRUCT 100
#define NP 4
#define NS 4
#define NF2 2560      // 4 l x 640 block-aligned symmetric-packed features
#define HID 256
#define APAD 10240    // 80 tiles of 128

// prep-kernel block ranges
#define PB_FEAT  2500                     // [0,2500): power spectrum, 4 atoms/block
#define PB_W0    (PB_FEAT + 2560)         // w0cvt: 8(n) x 80(k) x 4(p)
#define PB_W1    (PB_W0 + 256)            // w1cvt: 8 x 8 x 4
#define PB_ZERO  (PB_W1 + 300)            // fh tail rows 10000..10239
#define PB_TOTAL (PB_ZERO + 1)            // + out zero

typedef __attribute__((ext_vector_type(8))) _Float16 f16x8;
typedef __attribute__((ext_vector_type(8))) ushort u16x8;
typedef __attribute__((ext_vector_type(4))) float f32x4;

__device__ __forceinline__ float silu(float x) {
  return x / (1.f + __expf(-x));
}
__device__ __forceinline__ ushort f2h(float x) {
  _Float16 h = (_Float16)x;
  return *reinterpret_cast<ushort*>(&h);
}
// chunk c in [0,80) -> (row q, r-block b). Row q owns blocks q>>3 .. 3.
__device__ __forceinline__ void cdec(int c, int& q, int& b) {
  if (c < 32)      { q = c >> 2; b = c & 3; }
  else if (c < 56) { int x = c - 32; int j = (x * 171) >> 9; q = 8 + j; b = 1 + (x - j * 3); }
  else if (c < 72) { int x = c - 56; q = 16 + (x >> 1); b = 2 + (x & 1); }
  else             { q = 24 + (c - 72); b = 3; }
}

typedef __attribute__((address_space(3))) uint32_t lds_u32;
typedef const __attribute__((address_space(1))) uint32_t glb_u32;
__device__ __forceinline__ void glds16(const ushort* g, ushort* l) {
  __builtin_amdgcn_global_load_lds((glb_u32*)g, (lds_u32*)l, 16, 0, 0);
}

// ---------------- Kernel P: fused prep -------------------------------------
__global__ __launch_bounds__(256) void prep_kernel(
    const float* __restrict__ c0, const float* __restrict__ c1,
    const float* __restrict__ c2, const float* __restrict__ c3,
    const float* __restrict__ W0, const float* __restrict__ W1,
    ushort* __restrict__ fh, ushort* __restrict__ W0t,
    ushort* __restrict__ W1t, float* __restrict__ out) {
  __shared__ float shbuf[2048];   // feat: 4 waves x 512; cvt: 32x33
  int b = blockIdx.x;
  int tid = threadIdx.x;

  if (b < PB_FEAT) {
    // ---- power spectrum, one WAVE per atom, 5 chunks/lane ----
    int wv = tid >> 6, lane = tid & 63;
    int a = b * 4 + wv;
    float* cs = shbuf + wv * 512;
    for (int i = 0; i < 8; ++i) {
      int e = lane + i * 64;
      float v;
      if (e < 32)       v = c0[a * 32  + e];
      else if (e < 128) v = c1[a * 96  + (e - 32)];
      else if (e < 288) v = c2[a * 160 + (e - 128)];
      else              v = c3[a * 224 + (e - 288)];
      cs[e] = v;
    }
    __syncthreads();
    const float cg[4]  = {1.0f, 0.5773502691896258f, 0.4472135954999579f, 0.3779644730092272f};
    const int  off[4]  = {0, 32, 128, 288};
    const int  nm[4]   = {1, 3, 5, 7};
#pragma unroll
    for (int t = 0; t < 5; ++t) {
      int cc = lane + t * 64;           // [0,320), all lanes busy
      int l = cc / 80, c = cc - l * 80;
      int q, bb; cdec(c, q, bb);
      int rb = bb * 8;
      const float* base = cs + off[l];
      float s[8] = {0.f, 0.f, 0.f, 0.f, 0.f, 0.f, 0.f, 0.f};
      for (int m = 0; m < nm[l]; ++m) {
        float bq = base[m * 32 + q];
        float4 v0 = *reinterpret_cast<const float4*>(&base[m * 32 + rb]);
        float4 v1 = *reinterpret_cast<const float4*>(&base[m * 32 + rb + 4]);
        s[0] += bq * v0.x; s[1] += bq * v0.y; s[2] += bq * v0.z; s[3] += bq * v0.w;
        s[4] += bq * v1.x; s[5] += bq * v1.y; s[6] += bq * v1.z; s[7] += bq * v1.w;
      }
      u16x8 o;
#pragma unroll
      for (int u = 0; u < 8; ++u) o[u] = f2h(s[u] * cg[l]);
      *reinterpret_cast<u16x8*>(&fh[(size_t)a * NF2 + cc * 8]) = o;
    }
  } else if (b < PB_W0) {
    // ---- W0' fold -> W0t [p][h][fk] fp16 ----
    int idx = b - PB_FEAT;
    int nx = idx & 7;
    int rest = idx >> 3;
    int ky = rest % 80, p = rest / 80;
    int kt = ky * 32, nt = nx * 32;
    int lx = tid & 31, ly = tid >> 5;
    float (*t)[33] = (float(*)[33])shbuf;
    const float* src = W0 + (size_t)p * 4096 * HID;
#pragma unroll
    for (int i = 0; i < 4; ++i) {
      int kf = kt + ly + i * 8;
      int l = kf / 640, w = kf - l * 640;
      int c = w >> 3, s = w & 7;
      int q, bb; cdec(c, q, bb);
      int r = bb * 8 + s;
      float v = 0.f;
      if (r >= q) {
        v = src[(size_t)(l * 1024 + q * 32 + r) * HID + nt + lx];
        if (r > q) v += src[(size_t)(l * 1024 + r * 32 + q) * HID + nt + lx];
      }
      t[ly + i * 8][lx] = v;
    }
    __syncthreads();
    ushort* dst = W0t + (size_t)p * HID * NF2;
#pragma unroll
    for (int i = 0; i < 4; ++i)
      dst[(size_t)(nt + ly + i * 8) * NF2 + kt + lx] = f2h(t[lx][ly + i * 8]);
  } else if (b < PB_W1) {
    int idx = b - PB_W0;
    int nx = idx & 7, ky = (idx >> 3) & 7, p = idx >> 6;
    int kt = ky * 32, nt = nx * 32;
    int lx = tid & 31, ly = tid >> 5;
    float (*t)[33] = (float(*)[33])shbuf;
    const float* src = W1 + (size_t)p * HID * HID;
#pragma unroll
    for (int i = 0; i < 4; ++i)
      t[ly + i * 8][lx] = src[(size_t)(kt + ly + i * 8) * HID + nt + lx];
    __syncthreads();
    ushort* dst = W1t + (size_t)p * HID * HID;
#pragma unroll
    for (int i = 0; i < 4; ++i)
      dst[(size_t)(nt + ly + i * 8) * HID + kt + lx] = f2h(t[lx][ly + i * 8]);
  } else if (b < PB_ZERO) {
    int idx = b - PB_W1;
    size_t e = (size_t)idx * 2048 + tid * 8;
    u16x8 z = (u16x8){0, 0, 0, 0, 0, 0, 0, 0};
    *reinterpret_cast<u16x8*>(&fh[(size_t)N_ATOMS * NF2 + e]) = z;
  } else {
    if (tid < NSTRUCT) out[tid] = 0.f;
  }
}

// ---------------- Kernel B: fp16 MFMA GEMM0, 128x128, BK=32, K=2560 --------
__global__ __launch_bounds__(256) void gemm0_mfma(
    const ushort* __restrict__ fh, const ushort* __restrict__ W0t,
    const float* __restrict__ combW, const int* __restrict__ species,
    ushort* __restrict__ h0f) {
  __shared__ ushort As[64 * 64];   // 8KB
  __shared__ ushort Bs[64 * 64];   // 8KB
  int tid = threadIdx.x;
  int linear = blockIdx.y * 8 + blockIdx.x;
  int xc = linear & 7, sq = linear >> 3;
  int bm = ((sq >> 3) * 8 + xc) * 128;   // m-tile
  int bn = (sq & 7) * 128;               // n-tile
  int wid = tid >> 6, lane = tid & 63;
  int wm = (wid >> 1) * 64, wn = (wid & 1) * 64;
  int mh = wid >> 1, nh = wid & 1;

  int pr = tid >> 3, pc = tid & 7;
  int lg = pc ^ (pr & 7);
  int mhalf = lg >> 2, kc = lg & 3;
  const ushort* gaA1 = fh  + ((size_t)(bm + pr + 64 * mhalf) * NF2 + kc * 8);
  const ushort* gaA2 = gaA1 + (size_t)32 * NF2;
  const ushort* gaB1 = W0t + ((size_t)(bn + pr + 64 * mhalf) * NF2 + kc * 8);
  const ushort* gaB2 = gaB1 + (size_t)32 * NF2;
  ushort* lA = As + tid * 8;
  ushort* lB = Bs + tid * 8;

  f32x4 acc[4][4];
#pragma unroll
  for (int i = 0; i < 4; ++i)
#pragma unroll
    for (int j = 0; j < 4; ++j) acc[i][j] = (f32x4){0.f, 0.f, 0.f, 0.f};

  int mrow = lane & 15;
  int h7 = mrow & 7;
  int qv = lane >> 4;
  int pcA = ((mh << 2) | qv) ^ h7;
  int pcB = ((nh << 2) | qv) ^ h7;

  for (int k0 = 0; k0 < NF2; k0 += 32) {
    glds16(gaA1 + k0, lA);
    glds16(gaA2 + k0, lA + 2048);
    glds16(gaB1 + k0, lB);
    glds16(gaB2 + k0, lB + 2048);
    __syncthreads();

    f16x8 af[4], bf[4];
#pragma unroll
    for (int i = 0; i < 4; ++i) {
      af[i] = *reinterpret_cast<const f16x8*>(&As[(i * 16 + mrow) * 64 + pcA * 8]);
      bf[i] = *reinterpret_cast<const f16x8*>(&Bs[(i * 16 + mrow) * 64 + pcB * 8]);
    }
#pragma unroll
    for (int i = 0; i < 4; ++i)
#pragma unroll
      for (int j = 0; j < 4; ++j)
        acc[i][j] = __builtin_amdgcn_mfma_f32_16x16x32_f16(af[i], bf[j], acc[i][j], 0, 0, 0);
    __syncthreads();
  }

  int p = bn >> 8;
  int col = lane & 15, rbase = (lane >> 4) * 4;
#pragma unroll
  for (int i = 0; i < 4; ++i) {
#pragma unroll
    for (int r = 0; r < 4; ++r) {
      int m = bm + wm + i * 16 + rbase + r;
      bool live = (m < N_ATOMS);
      float pw = live ? combW[p * NS + species[m]] : 0.f;
#pragma unroll
      for (int j = 0; j < 4; ++j) {
        int n = bn + wn + j * 16 + col;
        float v = live ? silu(pw * acc[i][j][r]) : 0.f;
        h0f[(size_t)m * 1024 + n] = f2h(v);
      }
    }
  }
}

// ---------------- Kernel C: layer-1 MFMA, 64m x 256n(one p) per block ------
__global__ __launch_bounds__(256) void mlp1_mfma(
    const ushort* __restrict__ h0f, const ushort* __restrict__ W1t,
    const float* __restrict__ W2, const int* __restrict__ sid,
    float* __restrict__ out) {
  __shared__ ushort As[64 * 256];   // 32KB
  __shared__ float sout[NSTRUCT];
  int tid = threadIdx.x;
  int linear = blockIdx.x;                   // 0..639
  int xc = linear & 7, s = linear >> 3;      // s in [0,80)
  int p = s & 3, t = s >> 2;                 // t in [0,20)
  int bm = ((t >> 1) * 8 + xc) * 128 + (t & 1) * 64;   // 64-row tile
  int wid = tid >> 6, lane = tid & 63;
  int wn = wid * 64;                         // wave's n-quarter within p

  if (tid < NSTRUCT) sout[tid] = 0.f;

  int mrow = lane & 15;
  int qv = lane >> 4;
  int h7 = mrow & 7;

#pragma unroll
  for (int s8 = 0; s8 < 8; ++s8) {
    int d = s8 * 256 + tid;
    int r = d >> 5, pcs = d & 31;
    int lc = pcs ^ (r & 7);
    glds16(h0f + (size_t)(bm + r) * 1024 + p * 256 + lc * 8, As + d * 8);
  }

  const ushort* wb = W1t + (size_t)p * HID * HID;
  f16x8 breg[4][8];
#pragma unroll
  for (int j = 0; j < 4; ++j) {
    const ushort* row = wb + (size_t)(wn + j * 16 + mrow) * 256 + qv * 8;
#pragma unroll
    for (int ki = 0; ki < 8; ++ki)
      breg[j][ki] = *reinterpret_cast<const f16x8*>(row + ki * 32);
  }

  __syncthreads();   // drains glds16 + sout init visible

  f32x4 acc[4][4];
#pragma unroll
  for (int i = 0; i < 4; ++i)
#pragma unroll
    for (int j = 0; j < 4; ++j) acc[i][j] = (f32x4){0.f, 0.f, 0.f, 0.f};

#pragma unroll
  for (int ki = 0; ki < 8; ++ki) {
    f16x8 af[4];
#pragma unroll
    for (int i = 0; i < 4; ++i) {
      int row = i * 16 + mrow;
      int pc2 = (ki * 4 + qv) ^ h7;
      af[i] = *reinterpret_cast<const f16x8*>(&As[row * 256 + pc2 * 8]);
    }
#pragma unroll
    for (int i = 0; i < 4; ++i)
#pragma unroll
      for (int j = 0; j < 4; ++j)
        acc[i][j] = __builtin_amdgcn_mfma_f32_16x16x32_f16(af[i], breg[j][ki], acc[i][j], 0, 0, 0);
  }

  // fused layer-2 + segment-sum epilogue (LDS-staged)
  int col = lane & 15, quad = lane >> 4;
  float w2j[4];
#pragma unroll
  for (int j = 0; j < 4; ++j) w2j[j] = W2[p * 256 + wn + j * 16 + col];
#pragma unroll
  for (int i = 0; i < 4; ++i) {
#pragma unroll
    for (int r = 0; r < 4; ++r) {
      float v = silu(acc[i][0][r]) * w2j[0] + silu(acc[i][1][r]) * w2j[1]
              + silu(acc[i][2][r]) * w2j[2] + silu(acc[i][3][r]) * w2j[3];
      v += __shfl_xor(v, 1, 64);
      v += __shfl_xor(v, 2, 64);
      v += __shfl_xor(v, 4, 64);
      v += __shfl_xor(v, 8, 64);
      if (col == 0) {
        int m = bm + i * 16 + quad * 4 + r;
        if (m < N_ATOMS) atomicAdd(&sout[sid[m]], v);
      }
    }
  }
  __syncthreads();
  if (tid < NSTRUCT) {
    float v = sout[tid];
    if (v != 0.f) atomicAdd(&out[tid], v);
  }
}

extern "C" void kernel_launch(void* const* d_in, const int* in_sizes, int n_in,
                              void* d_out, int out_size, void* d_ws, size_t ws_size,
                              hipStream_t stream) {
  const float* c0      = (const float*)d_in[0];
  const float* c1      = (const float*)d_in[1];
  const float* c2      = (const float*)d_in[2];
  const float* c3      = (const float*)d_in[3];
  const int*   species = (const int*)d_in[4];
  const int*   sid     = (const int*)d_in[5];
  const float* combW   = (const float*)d_in[6];
  const float* W0      = (const float*)d_in[7];
  const float* W1      = (const float*)d_in[8];
  const float* W2      = (const float*)d_in[9];
  float*       out     = (float*)d_out;

  // ws: fh 52.4MB | W0t 5.2MB | W1t 0.5MB | h0f 21MB = ~79MB
  ushort* fh  = (ushort*)d_ws;
  ushort* W0t = fh  + (size_t)APAD * NF2;
  ushort* W1t = W0t + (size_t)NP * HID * NF2;
  ushort* h0f = W1t + (size_t)NP * HID * HID;

  prep_kernel<<<PB_TOTAL, 256, 0, stream>>>(c0, c1, c2, c3, W0, W1,
                                            fh, W0t, W1t, out);

  dim3 g2(8, APAD / 128);    // 8 n-tiles x 80 remapped slots
  gemm0_mfma<<<g2, 256, 0, stream>>>(fh, W0t, combW, species, h0f);

  mlp1_mfma<<<640, 256, 0, stream>>>(h0f, W1t, W2, sid, out);
}